// Round 4
// baseline (3193.237 us; speedup 1.0000x reference)
//
#include <hip/hip_runtime.h>

// Cvxpy_81174881894666: batched dual ascent (R4: fix register spill)
//   per batch b: 100 iters of
//     z = a^T lam;  y = sigmoid(-(c+z));  g = a y + b;  lam = max(lam+0.05 g, 0)
//   output y = sigmoid(-(c + a^T lam_final)), status = zeros(int32)
//
// R3 post-mortem: 256 thr x 128 A-floats/thread spilled (VGPR_Count=128 ==
// array size alone; WRITE_SIZE 94MB of spill traffic; occupancy scratch-capped
// at 24%; VALUBusy 17%). R4: 512 thr/block, 64 A-floats/thread (16 float4),
// __launch_bounds__(512,4) caps VGPR at 128 (est. use ~110) -> no spill,
// 16 waves/CU (2 blocks). A read once from HBM, register-resident thereafter.
//
// Tiling: tc=tid>>5 (0..15) owns cols [tc*16,tc*16+16); tr=tid&31 (0..31)
// owns rows [tr*4,tr*4+4). z-reduce: 2 thr/col (16 partials + shfl_xor(1)).
// g-reduce: 4 thr/row (4 partials + shfl_xor(1),(2)).

#define BB 2048
#define MM 128
#define NN 256
#define NITER 100
#define STEP_ 0.05f

__global__ __launch_bounds__(512, 4) void cvx_dual_ascent(
    const float* __restrict__ A,
    const float* __restrict__ Bv,
    const float* __restrict__ C,
    float* __restrict__ out)
{
    const int bi  = blockIdx.x;
    const int tid = threadIdx.x;
    const int tc  = tid >> 5;   // 0..15 column group (16 cols)
    const int tr  = tid & 31;   // 0..31 row group (4 rows)
    const int m0  = tr * 4;
    const int n0  = tc * 16;

    __shared__ float zp_s[32][260];  // z partials [tr][col], stride 260 (4-way worst)
    __shared__ float y_s[NN];
    __shared__ float gs[16][132];    // g partials [tc][row]
    __shared__ float lam_s[MM];

    // ---- load my 4x16 a-tile into registers (read once from HBM) ----
    const float* Ab = A + (size_t)bi * (MM * NN);
    float4 areg[4][4];
    #pragma unroll
    for (int i = 0; i < 4; ++i) {
        const float* rowp = Ab + (m0 + i) * NN + n0;
        #pragma unroll
        for (int j = 0; j < 4; ++j)
            areg[i][j] = *reinterpret_cast<const float4*>(rowp + 4 * j);
    }
    const int   col  = tid >> 1;       // P2: 2 threads per column
    const int   h    = tid & 1;
    const float c_r  = C[bi * NN + col];
    const int   row  = tid >> 2;       // P4: 4 threads per row
    const int   q    = tid & 3;
    const float b_r  = Bv[bi * MM + row];
    float lam_r = 0.f;                 // lam[row], replicated across the 4 threads

    if (tid < MM) lam_s[tid] = 0.f;
    __syncthreads();

    for (int it = 0; it <= NITER; ++it) {
        // ---- P1: z partials over my 4 rows x 16 cols ----
        const float4 lv = *reinterpret_cast<const float4*>(&lam_s[m0]);
        const float lamv[4] = {lv.x, lv.y, lv.z, lv.w};
        float zp[16];
        #pragma unroll
        for (int j = 0; j < 16; ++j) zp[j] = 0.f;
        #pragma unroll
        for (int i = 0; i < 4; ++i) {
            #pragma unroll
            for (int j = 0; j < 4; ++j) {
                zp[4*j+0] = fmaf(areg[i][j].x, lamv[i], zp[4*j+0]);
                zp[4*j+1] = fmaf(areg[i][j].y, lamv[i], zp[4*j+1]);
                zp[4*j+2] = fmaf(areg[i][j].z, lamv[i], zp[4*j+2]);
                zp[4*j+3] = fmaf(areg[i][j].w, lamv[i], zp[4*j+3]);
            }
        }
        #pragma unroll
        for (int j = 0; j < 4; ++j)
            *reinterpret_cast<float4*>(&zp_s[tr][n0 + 4*j]) =
                make_float4(zp[4*j], zp[4*j+1], zp[4*j+2], zp[4*j+3]);
        __syncthreads();  // B1

        // ---- P2: reduce z over 32 row-groups; 2 threads per column ----
        float z = 0.f;
        #pragma unroll
        for (int u = 0; u < 16; ++u) z += zp_s[h * 16 + u][col];
        z += __shfl_xor(z, 1);
        const float x = c_r + z;
        const float y = 1.0f / (1.0f + expf(x));   // sigmoid(-(c+z))

        if (it == NITER) {                          // uniform final exit
            if (h == 0) out[(size_t)bi * NN + col] = y;
            break;
        }
        if (h == 0) y_s[col] = y;
        __syncthreads();  // B2

        // ---- P3: g partials over my 16 cols, 4 rows ----
        float yv[16];
        #pragma unroll
        for (int j = 0; j < 4; ++j) {
            const float4 v = *reinterpret_cast<const float4*>(&y_s[n0 + 4*j]);
            yv[4*j] = v.x; yv[4*j+1] = v.y; yv[4*j+2] = v.z; yv[4*j+3] = v.w;
        }
        float4 g4;
        float* gp = &g4.x;
        #pragma unroll
        for (int k = 0; k < 4; ++k) {
            float acc = 0.f;
            #pragma unroll
            for (int j = 0; j < 4; ++j) {
                acc = fmaf(areg[k][j].x, yv[4*j+0], acc);
                acc = fmaf(areg[k][j].y, yv[4*j+1], acc);
                acc = fmaf(areg[k][j].z, yv[4*j+2], acc);
                acc = fmaf(areg[k][j].w, yv[4*j+3], acc);
            }
            gp[k] = acc;
        }
        *reinterpret_cast<float4*>(&gs[tc][m0]) = g4;
        __syncthreads();  // B3

        // ---- P4: reduce g over 16 col-groups; 4 threads per row ----
        float p = 0.f;
        #pragma unroll
        for (int u = 0; u < 4; ++u) p += gs[q * 4 + u][row];
        p += __shfl_xor(p, 1);
        p += __shfl_xor(p, 2);
        lam_r = fmaxf(fmaf(STEP_, p + b_r, lam_r), 0.f);
        if (q == 0) lam_s[row] = lam_r;
        __syncthreads();  // B4
    }

    if (tid == 0) out[(size_t)BB * NN + bi] = 0.0f;  // status[bi] = int32 0
}

extern "C" void kernel_launch(void* const* d_in, const int* in_sizes, int n_in,
                              void* d_out, int out_size, void* d_ws, size_t ws_size,
                              hipStream_t stream) {
    const float* A  = (const float*)d_in[0];  // [2048,128,256]
    const float* Bv = (const float*)d_in[1];  // [2048,128]
    const float* C  = (const float*)d_in[2];  // [2048,256]
    float* out = (float*)d_out;               // y [2048,256] f32 ++ status [2048]

    cvx_dual_ascent<<<dim3(BB), dim3(512), 0, stream>>>(A, Bv, C, out);
}

// Round 5
// 937.161 us; speedup vs baseline: 3.4074x; 3.4074x over previous
//
#include <hip/hip_runtime.h>

// Cvxpy_81174881894666: batched dual ascent (R5: defeat spill/remat)
//   per batch b: 100 iters of
//     z = a^T lam;  y = sigmoid(-(c+z));  g = a y + b;  lam = max(lam+0.05 g, 0)
//   output y = sigmoid(-(c + a^T lam_final)), status = zeros(int32)
//
// R3: 128 fl/thread -> spilled (WRITE 94MB). R4: 64 fl/thread + LB(512,4) ->
// compiler chose VGPR=64 for 8 waves/EU and REMATERIALIZED the A loads into
// the loop (FETCH 7.3GB = 27x A, VALUBusy 10%). R5 fix:
//   - __launch_bounds__(512,2): VGPR budget 256 >> ~110 needed, no pressure.
//   - asm volatile("" : "+v") pins each loaded A value: inline-asm results
//     cannot be rematerialized, so A stays register-resident across the loop.

#define BB 2048
#define MM 128
#define NN 256
#define NITER 100
#define STEP_ 0.05f

__global__ __launch_bounds__(512, 2) void cvx_dual_ascent(
    const float* __restrict__ A,
    const float* __restrict__ Bv,
    const float* __restrict__ C,
    float* __restrict__ out)
{
    const int bi  = blockIdx.x;
    const int tid = threadIdx.x;
    const int tc  = tid >> 5;   // 0..15 column group (16 cols)
    const int tr  = tid & 31;   // 0..31 row group (4 rows)
    const int m0  = tr * 4;
    const int n0  = tc * 16;

    __shared__ float zp_s[32][260];  // z partials [tr][col]
    __shared__ float y_s[NN];
    __shared__ float gs[16][132];    // g partials [tc][row]
    __shared__ float lam_s[MM];

    // ---- load my 4x16 a-tile into registers (read once from HBM) ----
    const float* Ab = A + (size_t)bi * (MM * NN);
    float4 areg[4][4];
    #pragma unroll
    for (int i = 0; i < 4; ++i) {
        const float* rowp = Ab + (m0 + i) * NN + n0;
        #pragma unroll
        for (int j = 0; j < 4; ++j)
            areg[i][j] = *reinterpret_cast<const float4*>(rowp + 4 * j);
    }
    // Pin: make each component an inline-asm result -> not rematerializable,
    // must stay live in VGPRs for the whole loop. Emits zero instructions.
    #pragma unroll
    for (int i = 0; i < 4; ++i) {
        #pragma unroll
        for (int j = 0; j < 4; ++j) {
            asm volatile("" : "+v"(areg[i][j].x));
            asm volatile("" : "+v"(areg[i][j].y));
            asm volatile("" : "+v"(areg[i][j].z));
            asm volatile("" : "+v"(areg[i][j].w));
        }
    }

    const int   col  = tid >> 1;       // P2: 2 threads per column
    const int   h    = tid & 1;
    const float c_r  = C[bi * NN + col];
    const int   row  = tid >> 2;       // P4: 4 threads per row
    const int   q    = tid & 3;
    const float b_r  = Bv[bi * MM + row];
    float lam_r = 0.f;                 // lam[row], replicated across its 4 threads

    if (tid < MM) lam_s[tid] = 0.f;
    __syncthreads();

    for (int it = 0; it <= NITER; ++it) {
        // ---- P1: z partials over my 4 rows x 16 cols ----
        const float4 lv = *reinterpret_cast<const float4*>(&lam_s[m0]);
        const float lamv[4] = {lv.x, lv.y, lv.z, lv.w};
        float zp[16];
        #pragma unroll
        for (int j = 0; j < 16; ++j) zp[j] = 0.f;
        #pragma unroll
        for (int i = 0; i < 4; ++i) {
            #pragma unroll
            for (int j = 0; j < 4; ++j) {
                zp[4*j+0] = fmaf(areg[i][j].x, lamv[i], zp[4*j+0]);
                zp[4*j+1] = fmaf(areg[i][j].y, lamv[i], zp[4*j+1]);
                zp[4*j+2] = fmaf(areg[i][j].z, lamv[i], zp[4*j+2]);
                zp[4*j+3] = fmaf(areg[i][j].w, lamv[i], zp[4*j+3]);
            }
        }
        #pragma unroll
        for (int j = 0; j < 4; ++j)
            *reinterpret_cast<float4*>(&zp_s[tr][n0 + 4*j]) =
                make_float4(zp[4*j], zp[4*j+1], zp[4*j+2], zp[4*j+3]);
        __syncthreads();  // B1

        // ---- P2: reduce z over 32 row-groups; 2 threads per column ----
        float z = 0.f;
        #pragma unroll
        for (int u = 0; u < 16; ++u) z += zp_s[h * 16 + u][col];
        z += __shfl_xor(z, 1);
        const float x = c_r + z;
        const float y = 1.0f / (1.0f + expf(x));   // sigmoid(-(c+z))

        if (it == NITER) {                          // uniform final exit
            if (h == 0) out[(size_t)bi * NN + col] = y;
            break;
        }
        if (h == 0) y_s[col] = y;
        __syncthreads();  // B2

        // ---- P3: g partials over my 16 cols, 4 rows ----
        float yv[16];
        #pragma unroll
        for (int j = 0; j < 4; ++j) {
            const float4 v = *reinterpret_cast<const float4*>(&y_s[n0 + 4*j]);
            yv[4*j] = v.x; yv[4*j+1] = v.y; yv[4*j+2] = v.z; yv[4*j+3] = v.w;
        }
        float4 g4;
        float* gp = &g4.x;
        #pragma unroll
        for (int k = 0; k < 4; ++k) {
            float acc = 0.f;
            #pragma unroll
            for (int j = 0; j < 4; ++j) {
                acc = fmaf(areg[k][j].x, yv[4*j+0], acc);
                acc = fmaf(areg[k][j].y, yv[4*j+1], acc);
                acc = fmaf(areg[k][j].z, yv[4*j+2], acc);
                acc = fmaf(areg[k][j].w, yv[4*j+3], acc);
            }
            gp[k] = acc;
        }
        *reinterpret_cast<float4*>(&gs[tc][m0]) = g4;
        __syncthreads();  // B3

        // ---- P4: reduce g over 16 col-groups; 4 threads per row ----
        float p = 0.f;
        #pragma unroll
        for (int u = 0; u < 4; ++u) p += gs[q * 4 + u][row];
        p += __shfl_xor(p, 1);
        p += __shfl_xor(p, 2);
        lam_r = fmaxf(fmaf(STEP_, p + b_r, lam_r), 0.f);
        if (q == 0) lam_s[row] = lam_r;
        __syncthreads();  // B4
    }

    if (tid == 0) out[(size_t)BB * NN + bi] = 0.0f;  // status[bi] = int32 0
}

extern "C" void kernel_launch(void* const* d_in, const int* in_sizes, int n_in,
                              void* d_out, int out_size, void* d_ws, size_t ws_size,
                              hipStream_t stream) {
    const float* A  = (const float*)d_in[0];  // [2048,128,256]
    const float* Bv = (const float*)d_in[1];  // [2048,128]
    const float* C  = (const float*)d_in[2];  // [2048,256]
    float* out = (float*)d_out;               // y [2048,256] f32 ++ status [2048]

    cvx_dual_ascent<<<dim3(BB), dim3(512), 0, stream>>>(A, Bv, C, out);
}

// Round 6
// 606.951 us; speedup vs baseline: 5.2611x; 1.5440x over previous
//
#include <hip/hip_runtime.h>

// Cvxpy_81174881894666: batched dual ascent (R6: wave-local g + lambda)
//   per batch b: 100 iters of
//     z = a^T lam;  y = sigmoid(-(c+z));  g = a y + b;  lam = max(lam+0.05 g, 0)
//   out: y = sigmoid(-(c + a^T lam_final)) [2048,256] f32, status int32 zeros.
//
// R5 post-mortem: pin fixed spill/remat (FETCH 7.3GB->133MB, dur 937us) but
// VALUBusy 34.7% — latency-bound on 4 barriers/iter + lambda LDS round-trip,
// LDS_BANK_CONFLICT 6.6e7 from strided partial reductions.
//
// R6: wave w owns 16 FULL rows [16w,16w+16); lane l holds cols [4l,4l+4)
// (areg[16] float4, pinned). g = a.y is then wave-complete: scrambled tree
// reduce (17 shfl, static indices only) leaves row (l>>2)&15's full sum in
// lane l; lambda lives in-wave (reg + per-wave lam_s[16] for P1 broadcast
// reads). Only z-partials + y broadcast cross waves -> 2 barriers/iter,
// LDS 43.5KB -> ~10KB.

#define BB 2048
#define MM 128
#define NN 256
#define NITER 100
#define STEP_ 0.05f

__global__ __launch_bounds__(512, 3) void cvx_dual_ascent(
    const float* __restrict__ A,
    const float* __restrict__ Bv,
    const float* __restrict__ C,
    float* __restrict__ out)
{
    const int bi  = blockIdx.x;
    const int tid = threadIdx.x;
    const int w   = tid >> 6;        // wave 0..7 -> rows [16w, 16w+16)
    const int l   = tid & 63;        // lane
    const int colq = l * 4;          // my 4 columns (A and y)
    const int myrow = (l >> 2) & 15; // row I own after the scrambled reduce

    __shared__ float zp_s[8][260];   // z partials [wave][col] (pad 260: P2 b32 reads conflict-free)
    __shared__ float y_s[NN];
    __shared__ float lam_s[8][16];   // per-wave lambda for P1 broadcast reads

    // ---- load my 16 row-slices of A (read once), pin in VGPRs ----
    const float* Ab = A + (size_t)bi * (MM * NN);
    float4 areg[16];
    #pragma unroll
    for (int i = 0; i < 16; ++i)
        areg[i] = *reinterpret_cast<const float4*>(Ab + (w * 16 + i) * NN + colq);
    #pragma unroll
    for (int i = 0; i < 16; ++i)
        asm volatile("" : "+v"(areg[i].x), "+v"(areg[i].y),
                          "+v"(areg[i].z), "+v"(areg[i].w));

    const float sb  = STEP_ * Bv[bi * MM + w * 16 + myrow];  // 0.05*b for my row
    const int   col = tid >> 1;       // P2: 2 threads per column
    const int   h   = tid & 1;
    const float c_r = C[bi * NN + col];
    float lam = 0.f;                  // lambda[my row], 4-replicated per row

    if (tid < 128) lam_s[tid >> 4][tid & 15] = 0.f;
    __syncthreads();

    for (int it = 0; it <= NITER; ++it) {
        // ---- P1: z partials for my 4 cols over my wave's 16 rows ----
        // lambda via 4 broadcast b128 reads from my wave's lam_s row.
        const float4 lv0 = *reinterpret_cast<const float4*>(&lam_s[w][0]);
        const float4 lv1 = *reinterpret_cast<const float4*>(&lam_s[w][4]);
        const float4 lv2 = *reinterpret_cast<const float4*>(&lam_s[w][8]);
        const float4 lv3 = *reinterpret_cast<const float4*>(&lam_s[w][12]);
        const float lamv[16] = {lv0.x, lv0.y, lv0.z, lv0.w,
                                lv1.x, lv1.y, lv1.z, lv1.w,
                                lv2.x, lv2.y, lv2.z, lv2.w,
                                lv3.x, lv3.y, lv3.z, lv3.w};
        float4 zp = make_float4(0.f, 0.f, 0.f, 0.f);
        #pragma unroll
        for (int i = 0; i < 16; ++i) {
            zp.x = fmaf(areg[i].x, lamv[i], zp.x);
            zp.y = fmaf(areg[i].y, lamv[i], zp.y);
            zp.z = fmaf(areg[i].z, lamv[i], zp.z);
            zp.w = fmaf(areg[i].w, lamv[i], zp.w);
        }
        *reinterpret_cast<float4*>(&zp_s[w][colq]) = zp;
        __syncthreads();  // B1

        // ---- P2: z = sum over 8 waves; 2 threads per column ----
        float z = zp_s[h * 4 + 0][col] + zp_s[h * 4 + 1][col]
                + zp_s[h * 4 + 2][col] + zp_s[h * 4 + 3][col];
        z += __shfl_xor(z, 1);
        const float y = 1.0f / (1.0f + expf(c_r + z));   // sigmoid(-(c+z))

        if (it == NITER) {                                // uniform exit
            if (h == 0) out[(size_t)bi * NN + col] = y;
            break;
        }
        if (h == 0) y_s[col] = y;
        __syncthreads();  // B2

        // ---- P3: g for my wave's 16 rows (wave-local, no barrier) ----
        const float4 y4 = *reinterpret_cast<const float4*>(&y_s[colq]);
        float p[16];
        #pragma unroll
        for (int k = 0; k < 16; ++k) {
            float acc =      areg[k].x * y4.x;
            acc = fmaf(areg[k].y, y4.y, acc);
            acc = fmaf(areg[k].z, y4.z, acc);
            p[k] = fmaf(areg[k].w, y4.w, acc);
        }
        // scrambled tree reduce: keep-half + send-other-half each round.
        // After 4 halving rounds + 2 butterfly rounds, lane l holds the
        // full 64-lane sum for row myrow = (l>>2)&15. Static indices only.
        const bool b5 = (l & 32) != 0;
        float q[8];
        #pragma unroll
        for (int k = 0; k < 8; ++k) {
            const float keep = b5 ? p[k + 8] : p[k];
            const float send = b5 ? p[k]     : p[k + 8];
            q[k] = keep + __shfl_xor(send, 32);
        }
        const bool b4 = (l & 16) != 0;
        float r2[4];
        #pragma unroll
        for (int k = 0; k < 4; ++k) {
            const float keep = b4 ? q[k + 4] : q[k];
            const float send = b4 ? q[k]     : q[k + 4];
            r2[k] = keep + __shfl_xor(send, 16);
        }
        const bool b3 = (l & 8) != 0;
        float s2[2];
        #pragma unroll
        for (int k = 0; k < 2; ++k) {
            const float keep = b3 ? r2[k + 2] : r2[k];
            const float send = b3 ? r2[k]     : r2[k + 2];
            s2[k] = keep + __shfl_xor(send, 8);
        }
        const bool b2 = (l & 4) != 0;
        {
            const float keep = b2 ? s2[1] : s2[0];
            const float send = b2 ? s2[0] : s2[1];
            float g = keep + __shfl_xor(send, 4);
            g += __shfl_xor(g, 2);
            g += __shfl_xor(g, 1);
            // lam += 0.05*(g + b); clamp at 0
            lam = fmaxf(fmaf(STEP_, g, lam) + sb, 0.f);
        }
        if ((l & 3) == 0) lam_s[w][myrow] = lam;   // in-wave publish for next P1
        // no barrier: lam_s[w] is read only by wave w
    }

    if (tid == 0) out[(size_t)BB * NN + bi] = 0.0f;  // status[bi] = int32 0
}

extern "C" void kernel_launch(void* const* d_in, const int* in_sizes, int n_in,
                              void* d_out, int out_size, void* d_ws, size_t ws_size,
                              hipStream_t stream) {
    const float* A  = (const float*)d_in[0];  // [2048,128,256]
    const float* Bv = (const float*)d_in[1];  // [2048,128]
    const float* C  = (const float*)d_in[2];  // [2048,256]
    float* out = (float*)d_out;               // y [2048,256] f32 ++ status [2048]

    cvx_dual_ascent<<<dim3(BB), dim3(512), 0, stream>>>(A, Bv, C, out);
}

// Round 7
// 474.970 us; speedup vs baseline: 6.7230x; 1.2779x over previous
//
#include <hip/hip_runtime.h>

// Cvxpy_81174881894666: batched dual ascent (R7: permlane reduce + fast sigmoid)
//   per batch b: 100 iters of
//     z = a^T lam;  y = sigmoid(-(c+z));  g = a y + b;  lam = max(lam+0.05 g, 0)
//   out: y = sigmoid(-(c + a^T lam_final)) [2048,256] f32, status int32 zeros.
//
// R6 post-mortem: VALU-issue-bound (VALUBusy 79%, conflicts 0, dur 607us).
// ~190 inst/lane/iter, 128 essential FMA. R7 cuts overhead:
//  - P3 tree rounds 1-2 via v_permlane32/16_swap (2 inst/k vs 4-5): the swap
//    IS the keep/send scramble (A'=own-lo|other's-lo, B'=own-hi|other's-hi;
//    A'+B' = pair-sum with different rows per lane half). Row map unchanged:
//    myrow=(l>>2)&15.
//  - sigmoid: __expf + v_rcp (1 ulp) instead of libm expf + exact div.

#define BB 2048
#define MM 128
#define NN 256
#define NITER 100
#define STEP_ 0.05f

typedef unsigned int u32;
typedef u32 u32x2 __attribute__((ext_vector_type(2)));

__device__ __forceinline__ void plane32_swap(float& a, float& b) {
    u32x2 r = __builtin_amdgcn_permlane32_swap(__float_as_uint(a), __float_as_uint(b), false, false);
    a = __uint_as_float(r[0]);
    b = __uint_as_float(r[1]);
}
__device__ __forceinline__ void plane16_swap(float& a, float& b) {
    u32x2 r = __builtin_amdgcn_permlane16_swap(__float_as_uint(a), __float_as_uint(b), false, false);
    a = __uint_as_float(r[0]);
    b = __uint_as_float(r[1]);
}

__global__ __launch_bounds__(512, 3) void cvx_dual_ascent(
    const float* __restrict__ A,
    const float* __restrict__ Bv,
    const float* __restrict__ C,
    float* __restrict__ out)
{
    const int bi  = blockIdx.x;
    const int tid = threadIdx.x;
    const int w   = tid >> 6;        // wave 0..7 -> rows [16w, 16w+16)
    const int l   = tid & 63;        // lane
    const int colq = l * 4;          // my 4 columns (A and y)
    const int myrow = (l >> 2) & 15; // row I own after the reduce

    __shared__ float zp_s[8][260];   // z partials [wave][col]
    __shared__ float y_s[NN];
    __shared__ float lam_s[8][16];   // per-wave lambda (wave-private)

    // ---- load my 16 row-slices of A (read once), pin in regs ----
    const float* Ab = A + (size_t)bi * (MM * NN);
    float4 areg[16];
    #pragma unroll
    for (int i = 0; i < 16; ++i)
        areg[i] = *reinterpret_cast<const float4*>(Ab + (w * 16 + i) * NN + colq);
    #pragma unroll
    for (int i = 0; i < 16; ++i)
        asm volatile("" : "+v"(areg[i].x), "+v"(areg[i].y),
                          "+v"(areg[i].z), "+v"(areg[i].w));

    const float sb  = STEP_ * Bv[bi * MM + w * 16 + myrow];  // 0.05*b for my row
    const int   col = tid >> 1;       // P2: 2 threads per column
    const int   h   = tid & 1;
    const float c_r = C[bi * NN + col];
    float lam = 0.f;                  // lambda[my row], quad-replicated

    if (tid < 128) lam_s[tid >> 4][tid & 15] = 0.f;
    __syncthreads();

    for (int it = 0; it <= NITER; ++it) {
        // ---- P1: z partials for my 4 cols over my wave's 16 rows ----
        const float4 lv0 = *reinterpret_cast<const float4*>(&lam_s[w][0]);
        const float4 lv1 = *reinterpret_cast<const float4*>(&lam_s[w][4]);
        const float4 lv2 = *reinterpret_cast<const float4*>(&lam_s[w][8]);
        const float4 lv3 = *reinterpret_cast<const float4*>(&lam_s[w][12]);
        const float lamv[16] = {lv0.x, lv0.y, lv0.z, lv0.w,
                                lv1.x, lv1.y, lv1.z, lv1.w,
                                lv2.x, lv2.y, lv2.z, lv2.w,
                                lv3.x, lv3.y, lv3.z, lv3.w};
        float4 zp = make_float4(0.f, 0.f, 0.f, 0.f);
        #pragma unroll
        for (int i = 0; i < 16; ++i) {
            zp.x = fmaf(areg[i].x, lamv[i], zp.x);
            zp.y = fmaf(areg[i].y, lamv[i], zp.y);
            zp.z = fmaf(areg[i].z, lamv[i], zp.z);
            zp.w = fmaf(areg[i].w, lamv[i], zp.w);
        }
        *reinterpret_cast<float4*>(&zp_s[w][colq]) = zp;
        __syncthreads();  // B1

        // ---- P2: z = sum over 8 waves; 2 threads per column ----
        float z = zp_s[h * 4 + 0][col] + zp_s[h * 4 + 1][col]
                + zp_s[h * 4 + 2][col] + zp_s[h * 4 + 3][col];
        z += __shfl_xor(z, 1);
        const float e = __expf(c_r + z);                    // v_exp-based
        const float y = __builtin_amdgcn_rcpf(1.0f + e);    // sigmoid(-(c+z))

        if (it == NITER) {                                  // uniform exit
            if (h == 0) out[(size_t)bi * NN + col] = y;
            break;
        }
        if (h == 0) y_s[col] = y;
        __syncthreads();  // B2

        // ---- P3: g for my wave's 16 rows (wave-local) ----
        const float4 y4 = *reinterpret_cast<const float4*>(&y_s[colq]);
        float p[16];
        #pragma unroll
        for (int k = 0; k < 16; ++k) {
            float acc =      areg[k].x * y4.x;
            acc = fmaf(areg[k].y, y4.y, acc);
            acc = fmaf(areg[k].z, y4.z, acc);
            p[k] = fmaf(areg[k].w, y4.w, acc);
        }
        // Round 1 (lane-pair l,l^32): permlane32_swap + add.
        // After: lanes<32 carry rows k (0..7), lanes>=32 rows k+8.
        float q[8];
        #pragma unroll
        for (int k = 0; k < 8; ++k) {
            float a0 = p[k], b0 = p[k + 8];
            plane32_swap(a0, b0);
            q[k] = a0 + b0;
        }
        // Round 2 (l,l^16): permlane16_swap + add. bit4 -> rows +4.
        float r2[4];
        #pragma unroll
        for (int k = 0; k < 4; ++k) {
            float a0 = q[k], b0 = q[k + 4];
            plane16_swap(a0, b0);
            r2[k] = a0 + b0;
        }
        // Round 3 (mask 8, scrambled): bit3 -> rows +2.
        const bool b3 = (l & 8) != 0;
        float s0, s1;
        {
            const float k0 = b3 ? r2[2] : r2[0];
            const float d0 = b3 ? r2[0] : r2[2];
            s0 = k0 + __shfl_xor(d0, 8);
            const float k1 = b3 ? r2[3] : r2[1];
            const float d1 = b3 ? r2[1] : r2[3];
            s1 = k1 + __shfl_xor(d1, 8);
        }
        // Round 4 (mask 4, scrambled): bit2 -> rows +1. Then replicate quads.
        const bool b2 = (l & 4) != 0;
        {
            const float keep = b2 ? s1 : s0;
            const float send = b2 ? s0 : s1;
            float g = keep + __shfl_xor(send, 4);
            g += __shfl_xor(g, 2);
            g += __shfl_xor(g, 1);
            lam = fmaxf(fmaf(STEP_, g, lam) + sb, 0.f);
        }
        if ((l & 3) == 0) lam_s[w][myrow] = lam;   // in-wave publish
        // no barrier: lam_s[w] read only by wave w (in-wave DS order)
    }

    if (tid == 0) out[(size_t)BB * NN + bi] = 0.0f;  // status[bi] = int32 0
}

extern "C" void kernel_launch(void* const* d_in, const int* in_sizes, int n_in,
                              void* d_out, int out_size, void* d_ws, size_t ws_size,
                              hipStream_t stream) {
    const float* A  = (const float*)d_in[0];  // [2048,128,256]
    const float* Bv = (const float*)d_in[1];  // [2048,128]
    const float* C  = (const float*)d_in[2];  // [2048,256]
    float* out = (float*)d_out;               // y [2048,256] f32 ++ status [2048]

    cvx_dual_ascent<<<dim3(BB), dim3(512), 0, stream>>>(A, Bv, C, out);
}